// Round 11
// baseline (701.421 us; speedup 1.0000x reference)
//
#include <hip/hip_runtime.h>

typedef __attribute__((ext_vector_type(8))) short short8;
typedef __attribute__((ext_vector_type(4))) float f32x4;
typedef unsigned int uint32;
typedef unsigned short u16;

#define CCH   256
#define BATCH 8
#define LFULL 4096
#define SKL   2050
#define BM    128
#define BN    128
#define LDK   72   // padded LDS stride for the (cold) reg-staged cls kernel

#define GSTRIDE ((size_t)BATCH * LFULL * CCH)  // elems per G(i) buffer
#define XSTR    ((size_t)LFULL * CCH)          // per-batch stride in G
#define SSTR    ((size_t)SKL * CCH)            // per-batch stride in P/S buffers
#define PSTR    ((size_t)BATCH * SKL * CCH)    // per-split stride in P

__device__ const int TOUT[20] = {4095,4093,4089,4081,4065,4033,3969,3841,3585,3073,
                                 3072,3070,3066,3058,3042,3010,2946,2818,2562,2050};

__device__ __forceinline__ u16 f2b(float f) {
  uint32 u = __float_as_uint(f);
  u += 0x7fff + ((u >> 16) & 1);
  return (u16)(u >> 16);
}
__device__ __forceinline__ float gatef(float h) {
  float hc = fmaxf(h, -30.0f);
  float q = __expf(-hc);
  return (1.0f - q) * __builtin_amdgcn_rcpf(fmaf(q, q, 1.0f));
}
__device__ __forceinline__ void glds16(const void* g, void* l) {
  __builtin_amdgcn_global_load_lds(
      (const __attribute__((address_space(1))) void*)g,
      (__attribute__((address_space(3))) void*)l, 16, 0, 0);
}
// bijective XCD-chunk swizzle (m204): hardware id -> logical work id
__device__ __forceinline__ int xcd_swz(int orig, int nwg) {
  int xcd = orig & 7, idx = orig >> 3;
  int q = nwg >> 3, r = nwg & 7;
  int base = (xcd < r) ? xcd * (q + 1) : r * (q + 1) + (xcd - r) * q;
  return base + idx;
}

// ---- compose W'_i = (R_{i-1} + I) @ W_i,tap  -> FRAGMENT-PACKED bf16 ------
// DWP_i layout (elems): [kt]16384 [ks]8192 [ny]4096 [wn]2048 [fn]512 [lane]8 [jj]
__global__ __launch_bounds__(256)
void compose_w(const float* __restrict__ res_w, const float* __restrict__ dil_w,
               u16* __restrict__ DWP) {
  __shared__ float As[32][256];
  int bx = blockIdx.x;
  int chunk = bx & 7, tap = (bx >> 3) & 1, bi = bx >> 4;  // bi 0..18 -> block i=bi+1
  int i = bi + 1;
  int co = threadIdx.x;
  int ci0 = chunk * 32;

  for (int idx = threadIdx.x; idx < 32 * 256; idx += 256) {
    int r = idx >> 8, m = idx & 255;
    float v = res_w[((size_t)(bi * 256 + ci0 + r)) * 256 + m];
    if (ci0 + r == m) v += 1.0f;
    As[r][m] = v;
  }
  __syncthreads();

  float acc[32];
  #pragma unroll
  for (int r = 0; r < 32; ++r) acc[r] = 0.0f;

  const float* Wb = dil_w + ((size_t)(i * 2 + tap) * 256) * 256 + co;
  for (int m4 = 0; m4 < 64; ++m4) {
    const float* wp = Wb + (size_t)m4 * 4 * 256;
    float w0 = wp[0], w1 = wp[256], w2 = wp[512], w3 = wp[768];
    #pragma unroll
    for (int r = 0; r < 32; ++r) {
      float4 a = *(const float4*)&As[r][m4 * 4];
      acc[r] = fmaf(a.x, w0, acc[r]);
      acc[r] = fmaf(a.y, w1, acc[r]);
      acc[r] = fmaf(a.z, w2, acc[r]);
      acc[r] = fmaf(a.w, w3, acc[r]);
    }
  }
  int kb = tap * 8 + chunk;                 // k>>5
  int kt = kb >> 1, ks = kb & 1;
  int ny = co >> 7, wn = (co >> 6) & 1, fn = (co >> 4) & 3, fr = co & 15;
  u16* ob = DWP + (size_t)bi * 131072 + kt * 16384 + ks * 8192 +
            ny * 4096 + wn * 2048 + fn * 512 + fr * 8;
  #pragma unroll
  for (int g = 0; g < 4; ++g) {             // fq group: lane = g*16+fr
    u16 tmp[8];
    #pragma unroll
    for (int jj = 0; jj < 8; ++jj) tmp[jj] = f2b(acc[g * 8 + jj]);
    *(uint4*)(ob + g * 128) = *(uint4*)tmp;
  }
}

// ---- b'_i = rb_{i-1} @ (W0_i + W1_i) + db_i  (fp32) ----
__global__ __launch_bounds__(256)
void compose_bias(const float* __restrict__ res_b, const float* __restrict__ dil_w,
                  const float* __restrict__ dil_b, float* __restrict__ Bc) {
  int bi = blockIdx.x, i = bi + 1, co = threadIdx.x;
  float acc = dil_b[(size_t)i * 256 + co];
  const float* W0 = dil_w + ((size_t)(i * 2 + 0) * 256) * 256;
  const float* W1 = dil_w + ((size_t)(i * 2 + 1) * 256) * 256;
  for (int m = 0; m < 256; ++m) {
    float rb = res_b[(size_t)bi * 256 + m];
    acc = fmaf(rb, W0[(size_t)m * 256 + co] + W1[(size_t)m * 256 + co], acc);
  }
  Bc[(size_t)bi * 256 + co] = acc;
}

// ---- block-0 rank-1 fold ----
__global__ __launch_bounds__(256)
void head0(const float* __restrict__ causal_w, const float* __restrict__ causal_b,
           const float* __restrict__ dil_w, const float* __restrict__ dil_b,
           float* __restrict__ U) {
  int co = threadIdx.x;
  float u0 = 0.f, u1 = 0.f, b0 = dil_b[co];
  for (int m = 0; m < 256; ++m) {
    float cwm = causal_w[m], cbm = causal_b[m];
    float w0 = dil_w[(size_t)m * 256 + co];
    float w1 = dil_w[(size_t)(256 + m) * 256 + co];
    u0 = fmaf(cwm, w0, u0);
    u1 = fmaf(cwm, w1, u1);
    b0 = fmaf(cbm, w0 + w1, b0);
  }
  U[co] = u0; U[256 + co] = u1; U[512 + co] = b0;
}

// ---- G0[b][t][c] = gate(in[t]*u0 + in[t+1]*u1 + b0) ----
__global__ __launch_bounds__(256)
void g0_init(const float* __restrict__ in, const float* __restrict__ U,
             u16* __restrict__ G0) {
  int t = blockIdx.x, b = blockIdx.y, co = threadIdx.x;
  float x0 = in[(size_t)b * LFULL + t];
  float x1 = in[(size_t)b * LFULL + t + 1];
  float h = fmaf(x0, U[co], fmaf(x1, U[256 + co], U[512 + co]));
  G0[((size_t)b * LFULL + t) * CCH + co] = f2b(gatef(h));
}

// ---- skip weights -> fragment-packed SWP -------------------------------
__global__ __launch_bounds__(256)
void pack_skipT(const float* __restrict__ w, u16* __restrict__ o) {
  int e = blockIdx.x * 256 + threadIdx.x;   // (i*256+ci)*256+co
  int co = e & 255, ci = (e >> 8) & 255, i = e >> 16;
  int kk = ci >> 6, ks = (ci >> 5) & 1, fq = (ci >> 3) & 3, jj = ci & 7;
  int ny = co >> 7, wn = (co >> 6) & 1, fn = (co >> 4) & 3, fr = co & 15;
  int lane = fq * 16 + fr;
  o[(size_t)i * 65536 + kk * 16384 + ks * 8192 + ny * 4096 + wn * 2048 +
    fn * 512 + lane * 8 + jj] = f2b(w[e]);
}
__global__ __launch_bounds__(256)
void pack_cls(const float* __restrict__ w, u16* __restrict__ o) {
  int e = blockIdx.x * 256 + threadIdx.x;   // ci*256+co
  int co = e & 255, ci = e >> 8;
  o[(size_t)co * 256 + ci] = f2b(w[e]);
}
__global__ __launch_bounds__(256)
void sbsum_k(const float* __restrict__ sb, float* __restrict__ o) {
  int n = threadIdx.x;
  float s = 0.f;
  for (int i = 0; i < 20; ++i) s += sb[(size_t)i * 256 + n];
  o[n] = s;
}

// ===== HOT: gate GEMM. A: LDS 3-buf 2-deep glds16; B: packed L2->reg =======
__global__ __launch_bounds__(256)
void gatem(const u16* __restrict__ Ain, int d, int Tout, int ntile,
           const u16* __restrict__ Wp, const float* __restrict__ bias,
           u16* __restrict__ Gout) {
  __shared__ u16 As[3][BM * 64];            // 48 KB

  const int tid = threadIdx.x;
  const int nwg = ntile * 16;
  const int wgid = xcd_swz(blockIdx.x, nwg);
  const int tx = wgid % ntile;
  const int rem = wgid / ntile;
  const int ny = rem & 1;
  const int bb = rem >> 1;

  const int t0 = tx * BM;
  const int n0 = ny * BN;
  const int lane = tid & 63, wv = tid >> 6;
  const int wm = wv >> 1, wn = wv & 1;
  const int fr = lane & 15, fq = lane >> 4;
  const int rl = lane >> 3;
  const int subx = ((lane & 7) ^ rl) * 8;
  const int rowb = wv * 32;

  const u16* Ab = Ain + (size_t)bb * XSTR;
  const u16* Wbase = Wp + (size_t)ny * 4096 + wn * 2048 + lane * 8;

  f32x4 acc[4][4];
  #pragma unroll
  for (int fn = 0; fn < 4; ++fn) {
    float4 bv = *(const float4*)&bias[n0 + wn * 64 + fn * 16 + fq * 4];
    #pragma unroll
    for (int fm = 0; fm < 4; ++fm) acc[fm][fn] = (f32x4){bv.x, bv.y, bv.z, bv.w};
  }

  auto STAGE_A = [&](int kt, int sel) {
    const int tap = kt >> 2, ks0 = (kt & 3) * 64;
    #pragma unroll
    for (int qq = 0; qq < 4; ++qq) {
      int rr = rowb + qq * 8 + rl;
      int t = t0 + rr;
      if (t > Tout - 1) t = Tout - 1;
      glds16(Ab + (size_t)(t + tap * d) * CCH + ks0 + subx,
             &As[sel][(rowb + qq * 8) * 64]);
    }
  };
  auto LOADB = [&](int kt, short8* br) {
    const u16* base = Wbase + (size_t)kt * 16384;
    #pragma unroll
    for (int ks = 0; ks < 2; ++ks)
      #pragma unroll
      for (int fn = 0; fn < 4; ++fn)
        br[fn * 2 + ks] = *(const short8*)(base + ks * 8192 + fn * 512);
  };

  short8 b0r[8], b1r[8];
  LOADB(0, b0r);        // queue: B(0)
  STAGE_A(0, 0);        // queue: B(0),A(0)
  STAGE_A(1, 1);        // queue: B(0),A(0),A(1)

  // steady queue entering wait: A(kt),B(kt),A(kt+1),B(kt+1),A(kt+2) = 28
  // vmcnt(16) drains exactly A(kt)+B(kt); A got 2 iterations of cover.
  #pragma unroll
  for (int kt = 0; kt < 8; ++kt) {
    short8* bc = (kt & 1) ? b1r : b0r;
    short8* bn = (kt & 1) ? b0r : b1r;
    if (kt < 7) LOADB(kt + 1, bn);
    if (kt < 6) {
      STAGE_A(kt + 2, (kt + 2) % 3);
      asm volatile("s_waitcnt vmcnt(16)" ::: "memory");
    } else if (kt == 6) {
      asm volatile("s_waitcnt vmcnt(12)" ::: "memory");
    } else {
      asm volatile("s_waitcnt vmcnt(0)" ::: "memory");
    }
    __builtin_amdgcn_s_barrier();
    __builtin_amdgcn_sched_barrier(0);

    const int cur = kt % 3;
    #pragma unroll
    for (int ks = 0; ks < 2; ++ks) {
      short8 af[4];
      #pragma unroll
      for (int fm = 0; fm < 4; ++fm) {
        int row = wm * 64 + fm * 16 + fr;
        af[fm] = *(const short8*)&As[cur][row * 64 + ((ks * 4 + fq) ^ (row & 7)) * 8];
      }
      #pragma unroll
      for (int fm = 0; fm < 4; ++fm)
        #pragma unroll
        for (int fn = 0; fn < 4; ++fn)
          acc[fm][fn] = __builtin_amdgcn_mfma_f32_16x16x32_bf16(   // SWAPPED ->
              bc[fn * 2 + ks], af[fm], acc[fm][fn], 0, 0, 0);      // D^T layout
    }
    __builtin_amdgcn_s_barrier();   // As[kt%3] is restaged next iteration
  }

  // D^T: t = t0+wm*64+fm*16+fr ; cout quad = n0+wn*64+fn*16+fq*4
  u16* Ob = Gout + (size_t)bb * XSTR;
  #pragma unroll
  for (int fm = 0; fm < 4; ++fm) {
    int t = t0 + wm * 64 + fm * 16 + fr;
    if (t >= Tout) continue;
    #pragma unroll
    for (int fn = 0; fn < 4; ++fn) {
      int c0 = n0 + wn * 64 + fn * 16 + fq * 4;
      f32x4 a = acc[fm][fn];
      uint32 p0 = (uint32)f2b(gatef(a[0])) | ((uint32)f2b(gatef(a[1])) << 16);
      uint32 p1 = (uint32)f2b(gatef(a[2])) | ((uint32)f2b(gatef(a[3])) << 16);
      uint2 pk; pk.x = p0; pk.y = p1;
      *(uint2*)(Ob + (size_t)t * CCH + c0) = pk;
    }
  }
}

// ===== HOT: deferred-skip mega-GEMM, 3-buf 2-deep A + packed B-reg =========
__global__ __launch_bounds__(256)
void skipm(const u16* __restrict__ Gh, const u16* __restrict__ SWP,
           float* __restrict__ P) {
  __shared__ u16 As[3][BM * 64];

  const int tid = threadIdx.x;
  const int nwg = 17 * 2 * 32;
  const int wgid = xcd_swz(blockIdx.x, nwg);
  const int tx = wgid % 17;
  const int rem = wgid / 17;
  const int ny = rem & 1;
  const int zz = rem >> 1;
  const int b = zz >> 2, j = zz & 3;

  const int t0 = tx * BM;
  const int n0 = ny * BN;
  const int lane = tid & 63, wv = tid >> 6;
  const int wm = wv >> 1, wn = wv & 1;
  const int fr = lane & 15, fq = lane >> 4;
  const int rl = lane >> 3;
  const int subx = ((lane & 7) ^ rl) * 8;
  const int rowb = wv * 32;

  const u16* Gb = Gh + (size_t)b * XSTR;
  const u16* Wbase = SWP + (size_t)ny * 4096 + wn * 2048 + lane * 8;

  f32x4 acc[4][4];
  #pragma unroll
  for (int fm = 0; fm < 4; ++fm)
    #pragma unroll
    for (int fn = 0; fn < 4; ++fn) acc[fm][fn] = (f32x4){0.f, 0.f, 0.f, 0.f};

  auto STAGE_A = [&](int kt, int sel) {
    const int i = j * 5 + (kt >> 2);
    const int toff = TOUT[i] - SKL;
    const int ks0 = (kt & 3) * 64;
    const u16* Gi = Gb + (size_t)i * GSTRIDE;
    #pragma unroll
    for (int qq = 0; qq < 4; ++qq) {
      int rr = rowb + qq * 8 + rl;
      int t = t0 + rr;
      if (t > SKL - 1) t = SKL - 1;
      glds16(Gi + (size_t)(toff + t) * CCH + ks0 + subx,
             &As[sel][(rowb + qq * 8) * 64]);
    }
  };
  auto LOADB = [&](int kt, short8* br) {
    const int i = j * 5 + (kt >> 2), kk = kt & 3;
    const u16* base = Wbase + (size_t)i * 65536 + kk * 16384;
    #pragma unroll
    for (int ks = 0; ks < 2; ++ks)
      #pragma unroll
      for (int fn = 0; fn < 4; ++fn)
        br[fn * 2 + ks] = *(const short8*)(base + ks * 8192 + fn * 512);
  };

  short8 b0r[8], b1r[8];
  LOADB(0, b0r);
  STAGE_A(0, 0);
  STAGE_A(1, 1);

  #pragma unroll
  for (int kt = 0; kt < 20; ++kt) {
    short8* bc = (kt & 1) ? b1r : b0r;
    short8* bn = (kt & 1) ? b0r : b1r;
    if (kt < 19) LOADB(kt + 1, bn);
    if (kt < 18) {
      STAGE_A(kt + 2, (kt + 2) % 3);
      asm volatile("s_waitcnt vmcnt(16)" ::: "memory");
    } else if (kt == 18) {
      asm volatile("s_waitcnt vmcnt(12)" ::: "memory");
    } else {
      asm volatile("s_waitcnt vmcnt(0)" ::: "memory");
    }
    __builtin_amdgcn_s_barrier();
    __builtin_amdgcn_sched_barrier(0);

    const int cur = kt % 3;
    #pragma unroll
    for (int ks = 0; ks < 2; ++ks) {
      short8 af[4];
      #pragma unroll
      for (int fm = 0; fm < 4; ++fm) {
        int row = wm * 64 + fm * 16 + fr;
        af[fm] = *(const short8*)&As[cur][row * 64 + ((ks * 4 + fq) ^ (row & 7)) * 8];
      }
      #pragma unroll
      for (int fm = 0; fm < 4; ++fm)
        #pragma unroll
        for (int fn = 0; fn < 4; ++fn)
          acc[fm][fn] = __builtin_amdgcn_mfma_f32_16x16x32_bf16(
              bc[fn * 2 + ks], af[fm], acc[fm][fn], 0, 0, 0);   // D^T
    }
    __builtin_amdgcn_s_barrier();
  }

  float* Pj = P + (size_t)j * PSTR + (size_t)b * SSTR;
  #pragma unroll
  for (int fm = 0; fm < 4; ++fm) {
    int t = t0 + wm * 64 + fm * 16 + fr;
    if (t >= SKL) continue;
    #pragma unroll
    for (int fn = 0; fn < 4; ++fn) {
      int c0 = n0 + wn * 64 + fn * 16 + fq * 4;
      f32x4 a = acc[fm][fn];
      float4 o = {a[0], a[1], a[2], a[3]};
      *(float4*)(Pj + (size_t)t * CCH + c0) = o;
    }
  }
}

// ============ cold cls GEMMs: reg-staged (transform fused in stage) ========
enum { MODE_CLS1 = 1, MODE_CLS2 = 2 };

template <int MODE>
__global__ __launch_bounds__(256)
void convm(const void* __restrict__ Ainv, long a_bstride,
           const u16* __restrict__ Wt, const float* __restrict__ bias,
           const float* __restrict__ extra,
           void* __restrict__ Out1, long out_bstride, int Tout) {
  __shared__ u16 As[BM * LDK];
  __shared__ u16 Bs[BN * LDK];

  const int tid = threadIdx.x;
  const int bb  = blockIdx.z;
  const int t0  = blockIdx.x * BM;
  const int n0  = blockIdx.y * BN;
  const int lane = tid & 63, wv = tid >> 6;
  const int wm = wv >> 1, wn = wv & 1;
  const int fr = lane & 15, fq = lane >> 4;

  f32x4 acc[4][4];
  #pragma unroll
  for (int fn = 0; fn < 4; ++fn) {
    float bv = bias[n0 + wn * 64 + fn * 16 + fr];
    #pragma unroll
    for (int fm = 0; fm < 4; ++fm) acc[fm][fn] = (f32x4){bv, bv, bv, bv};
  }

  for (int kt = 0; kt < 4; ++kt) {
    for (int idx = tid; idx < 1024; idx += 256) {
      int r = idx >> 3, c8 = idx & 7;
      int t = t0 + r; if (t > Tout - 1) t = Tout - 1;
      uint4 v;
      if constexpr (MODE == MODE_CLS1) {
        const float* p0 = (const float*)Ainv + (size_t)bb * a_bstride +
                          (size_t)t * CCH + kt * 64 + c8 * 8;
        float4 s0 = *(const float4*)p0;
        float4 s1 = *(const float4*)(p0 + 4);
        #pragma unroll
        for (int jj = 1; jj < 4; ++jj) {
          const float* pj = p0 + (size_t)jj * PSTR;
          float4 a0 = *(const float4*)pj;
          float4 a1 = *(const float4*)(pj + 4);
          s0.x += a0.x; s0.y += a0.y; s0.z += a0.z; s0.w += a0.w;
          s1.x += a1.x; s1.y += a1.y; s1.z += a1.z; s1.w += a1.w;
        }
        float4 e0 = *(const float4*)&extra[kt * 64 + c8 * 8];
        float4 e1 = *(const float4*)&extra[kt * 64 + c8 * 8 + 4];
        u16 tmp[8];
        tmp[0] = f2b(fmaxf((s0.x + e0.x) * 0.05f, 0.f));
        tmp[1] = f2b(fmaxf((s0.y + e0.y) * 0.05f, 0.f));
        tmp[2] = f2b(fmaxf((s0.z + e0.z) * 0.05f, 0.f));
        tmp[3] = f2b(fmaxf((s0.w + e0.w) * 0.05f, 0.f));
        tmp[4] = f2b(fmaxf((s1.x + e1.x) * 0.05f, 0.f));
        tmp[5] = f2b(fmaxf((s1.y + e1.y) * 0.05f, 0.f));
        tmp[6] = f2b(fmaxf((s1.z + e1.z) * 0.05f, 0.f));
        tmp[7] = f2b(fmaxf((s1.w + e1.w) * 0.05f, 0.f));
        v = *(uint4*)tmp;
      } else {
        const u16* sp = (const u16*)Ainv + (size_t)bb * a_bstride +
                        (size_t)t * CCH + kt * 64 + c8 * 8;
        uint4 raw = *(const uint4*)sp;
        u16 tmp[8];
        *(uint4*)tmp = raw;
        #pragma unroll
        for (int jj = 0; jj < 8; ++jj) tmp[jj] = (tmp[jj] & 0x8000) ? (u16)0 : tmp[jj];
        v = *(uint4*)tmp;
      }
      *(uint4*)&As[r * LDK + c8 * 8] = v;
    }
    for (int idx = tid; idx < 1024; idx += 256) {
      int r = idx >> 3, c8 = idx & 7;
      const u16* sp = Wt + (size_t)(n0 + r) * 256 + kt * 64 + c8 * 8;
      *(uint4*)&Bs[r * LDK + c8 * 8] = *(const uint4*)sp;
    }
    __syncthreads();

    #pragma unroll
    for (int ks = 0; ks < 2; ++ks) {
      short8 af[4], bfr[4];
      #pragma unroll
      for (int fm = 0; fm < 4; ++fm)
        af[fm] = *(const short8*)&As[(wm * 64 + fm * 16 + fr) * LDK + ks * 32 + fq * 8];
      #pragma unroll
      for (int fn = 0; fn < 4; ++fn)
        bfr[fn] = *(const short8*)&Bs[(wn * 64 + fn * 16 + fr) * LDK + ks * 32 + fq * 8];
      #pragma unroll
      for (int fm = 0; fm < 4; ++fm)
        #pragma unroll
        for (int fn = 0; fn < 4; ++fn)
          acc[fm][fn] = __builtin_amdgcn_mfma_f32_16x16x32_bf16(
              af[fm], bfr[fn], acc[fm][fn], 0, 0, 0);
    }
    __syncthreads();
  }

  #pragma unroll
  for (int fm = 0; fm < 4; ++fm) {
    int rbase = t0 + wm * 64 + fm * 16 + fq * 4;
    #pragma unroll
    for (int r = 0; r < 4; ++r) {
      int t = rbase + r;
      if (t >= Tout) continue;
      #pragma unroll
      for (int fn = 0; fn < 4; ++fn) {
        int c = n0 + wn * 64 + fn * 16 + fr;
        float a = acc[fm][fn][r];
        size_t oix = (size_t)bb * out_bstride + (size_t)t * CCH + c;
        if constexpr (MODE == MODE_CLS1) {
          ((u16*)Out1)[oix] = f2b(a);
        } else {
          ((float*)Out1)[oix] = a;
        }
      }
    }
  }
}

// ---------------- dense head (fp32, memory-bound on 537MB weights) --------
__global__ __launch_bounds__(256)
void dense_partial(const float* __restrict__ f, const float* __restrict__ W,
                   float* __restrict__ part) {
  int tstep = blockIdx.x;
  int n = threadIdx.x;
  __shared__ float fs[BATCH][CCH];
  for (int idx = threadIdx.x; idx < BATCH * CCH; idx += 256) {
    int b = idx >> 8, c = idx & 255;
    fs[b][c] = f[((size_t)b * SKL + tstep) * CCH + c];
  }
  __syncthreads();
  float acc[BATCH] = {0.f, 0.f, 0.f, 0.f, 0.f, 0.f, 0.f, 0.f};
  const float* Wr = W + (size_t)tstep * CCH * CCH;
  for (int ci = 0; ci < CCH; ++ci) {
    float w = Wr[(size_t)ci * CCH + n];
    #pragma unroll
    for (int b = 0; b < BATCH; ++b) acc[b] = fmaf(fs[b][ci], w, acc[b]);
  }
  #pragma unroll
  for (int b = 0; b < BATCH; ++b)
    part[((size_t)tstep * BATCH + b) * CCH + n] = acc[b];
}

__global__ __launch_bounds__(256)
void reduce_part(const float* __restrict__ part, float* __restrict__ part2) {
  int chunk = blockIdx.x, b = blockIdx.y, n = threadIdx.x;
  int c0 = chunk * 33;
  int c1 = c0 + 33; if (c1 > SKL) c1 = SKL;
  float s = 0.f;
  for (int c = c0; c < c1; ++c) s += part[((size_t)c * BATCH + b) * CCH + n];
  part2[((size_t)b * 64 + chunk) * CCH + n] = s;
}

__global__ __launch_bounds__(256)
void softmax_k(const float* __restrict__ part2, const float* __restrict__ db,
               float* __restrict__ out) {
  int b = blockIdx.x, n = threadIdx.x;
  float s = db[n];
  for (int ch = 0; ch < 64; ++ch) s += part2[((size_t)b * 64 + ch) * CCH + n];

  __shared__ float r4[4];
  __shared__ float mglob, sglob;
  int wid = n >> 6, lane = n & 63;

  float m = s;
  #pragma unroll
  for (int off = 1; off < 64; off <<= 1) m = fmaxf(m, __shfl_xor(m, off));
  if (lane == 0) r4[wid] = m;
  __syncthreads();
  if (n == 0) mglob = fmaxf(fmaxf(r4[0], r4[1]), fmaxf(r4[2], r4[3]));
  __syncthreads();

  float e = expf(s - mglob);
  float se = e;
  #pragma unroll
  for (int off = 1; off < 64; off <<= 1) se += __shfl_xor(se, off);
  if (lane == 0) r4[wid] = se;
  __syncthreads();
  if (n == 0) sglob = r4[0] + r4[1] + r4[2] + r4[3];
  __syncthreads();

  out[(size_t)b * CCH + n] = e / sglob;
}

extern "C" void kernel_launch(void* const* d_in, const int* in_sizes, int n_in,
                              void* d_out, int out_size, void* d_ws, size_t ws_size,
                              hipStream_t stream) {
  const float* input_x  = (const float*)d_in[0];
  const float* causal_w = (const float*)d_in[1];
  const float* causal_b = (const float*)d_in[2];
  const float* dil_w    = (const float*)d_in[3];
  const float* dil_b    = (const float*)d_in[4];
  const float* res_w    = (const float*)d_in[5];
  const float* res_b    = (const float*)d_in[6];
  const float* skip_w   = (const float*)d_in[7];
  const float* skip_b   = (const float*)d_in[8];
  const float* cls_w    = (const float*)d_in[9];
  const float* cls_b    = (const float*)d_in[10];
  const float* dense_w  = (const float*)d_in[11];
  const float* dense_b  = (const float*)d_in[12];
  float* out = (float*)d_out;

  // ---- workspace layout ----
  char* p = (char*)d_ws;
  u16*   Gh    = (u16*)p;   p += GSTRIDE * 20 * 2;                 // 335 MB
  float* P     = (float*)p; p += PSTR * 4 * 4;                     // 67 MB
  u16*   S1    = (u16*)p;   p += (size_t)BATCH * SKL * CCH * 2;
  float* S2    = (float*)p; p += (size_t)BATCH * SKL * CCH * 4;
  float* PART  = (float*)p; p += (size_t)SKL * BATCH * CCH * 4;
  float* PART2 = (float*)p; p += (size_t)BATCH * 64 * CCH * 4;
  u16*   DWP   = (u16*)p;   p += (size_t)19 * 131072 * 2;
  float* Bc    = (float*)p; p += (size_t)19 * 256 * 4;
  u16*   SWP   = (u16*)p;   p += (size_t)20 * 65536 * 2;
  u16*   CW    = (u16*)p;   p += (size_t)256 * 256 * 2;
  float* U     = (float*)p; p += (size_t)768 * 4;
  float* SBS   = (float*)p; p += (size_t)256 * 4;

  static const int dil[20] = {1, 2, 4, 8, 16, 32, 64, 128, 256, 512,
                              1, 2, 4, 8, 16, 32, 64, 128, 256, 512};
  static const int tout_h[20] = {4095,4093,4089,4081,4065,4033,3969,3841,3585,3073,
                                 3072,3070,3066,3058,3042,3010,2946,2818,2562,2050};
  dim3 blk(256);
  const int stile = (SKL + BM - 1) / BM;   // 17 skip tiles

  compose_w   <<<dim3(19 * 2 * 8), blk, 0, stream>>>(res_w, dil_w, DWP);
  compose_bias<<<dim3(19), blk, 0, stream>>>(res_b, dil_w, dil_b, Bc);
  head0       <<<dim3(1), blk, 0, stream>>>(causal_w, causal_b, dil_w, dil_b, U);
  pack_skipT  <<<dim3(20 * 256), blk, 0, stream>>>(skip_w, SWP);
  pack_cls    <<<dim3(256), blk, 0, stream>>>(cls_w, CW);
  sbsum_k     <<<dim3(1), blk, 0, stream>>>(skip_b, SBS);

  g0_init<<<dim3(4095, BATCH), blk, 0, stream>>>(input_x, U, Gh);

  // 19 composed gate GEMMs (1D swizzled grid; per-dispatch, graph-replayed)
  for (int i = 1; i < 20; ++i) {
    int Tout = tout_h[i];
    int ntile = (Tout + BM - 1) / BM;
    gatem<<<dim3(ntile * 16), blk, 0, stream>>>(
        Gh + (size_t)(i - 1) * GSTRIDE, dil[i], Tout, ntile,
        DWP + (size_t)(i - 1) * 131072, Bc + (size_t)(i - 1) * 256,
        Gh + (size_t)i * GSTRIDE);
  }

  // deferred skip mega-GEMM (K=5120 split x4 into fp32 partials, write-once)
  skipm<<<dim3(17 * 2 * 32), blk, 0, stream>>>(Gh, SWP, P);

  convm<MODE_CLS1><<<dim3(stile, 2, BATCH), blk, 0, stream>>>(
      P, (long)SSTR, CW, cls_b, SBS, S1, (long)SSTR, SKL);
  convm<MODE_CLS2><<<dim3(stile, 2, BATCH), blk, 0, stream>>>(
      S1, (long)SSTR, CW, cls_b, nullptr, S2, (long)SSTR, SKL);

  dense_partial<<<dim3(SKL), blk, 0, stream>>>(S2, dense_w, PART);
  reduce_part<<<dim3(64, BATCH), blk, 0, stream>>>(PART, PART2);
  softmax_k<<<dim3(BATCH), blk, 0, stream>>>(PART2, dense_b, out);
}

// Round 12
// 670.898 us; speedup vs baseline: 1.0455x; 1.0455x over previous
//
#include <hip/hip_runtime.h>

typedef __attribute__((ext_vector_type(8))) short short8;
typedef __attribute__((ext_vector_type(4))) float f32x4;
typedef unsigned int uint32;
typedef unsigned short u16;

#define CCH   256
#define BATCH 8
#define LFULL 4096
#define SKL   2050
#define BM    64   // halved: doubles grid, 2-4 blocks/CU
#define BN    128
#define LDKC  72   // padded LDS stride for the (cold) reg-staged cls kernel

#define GSTRIDE ((size_t)BATCH * LFULL * CCH)
#define XSTR    ((size_t)LFULL * CCH)
#define SSTR    ((size_t)SKL * CCH)
#define PSTR    ((size_t)BATCH * SKL * CCH)

__device__ const int TOUT[20] = {4095,4093,4089,4081,4065,4033,3969,3841,3585,3073,
                                 3072,3070,3066,3058,3042,3010,2946,2818,2562,2050};

__device__ __forceinline__ u16 f2b(float f) {
  uint32 u = __float_as_uint(f);
  u += 0x7fff + ((u >> 16) & 1);
  return (u16)(u >> 16);
}
__device__ __forceinline__ float gatef(float h) {
  float hc = fmaxf(h, -30.0f);
  float q = __expf(-hc);
  return (1.0f - q) * __builtin_amdgcn_rcpf(fmaf(q, q, 1.0f));
}
__device__ __forceinline__ void glds16(const void* g, void* l) {
  __builtin_amdgcn_global_load_lds(
      (const __attribute__((address_space(1))) void*)g,
      (__attribute__((address_space(3))) void*)l, 16, 0, 0);
}
__device__ __forceinline__ int xcd_swz(int orig, int nwg) {
  int xcd = orig & 7, idx = orig >> 3;
  int q = nwg >> 3, r = nwg & 7;
  int base = (xcd < r) ? xcd * (q + 1) : r * (q + 1) + (xcd - r) * q;
  return base + idx;
}

// ===== merged prep: compose_w | pack_skipT | pack_cls | compose_bias |
//                    head0 | sbsum_k  (all independent; one dispatch) =======
__global__ __launch_bounds__(256)
void prep_all(const float* __restrict__ res_w, const float* __restrict__ dil_w,
              const float* __restrict__ dil_b, const float* __restrict__ res_b,
              const float* __restrict__ causal_w, const float* __restrict__ causal_b,
              const float* __restrict__ skip_w, const float* __restrict__ cls_w,
              const float* __restrict__ skip_b,
              u16* __restrict__ DWP, float* __restrict__ Bc, float* __restrict__ U,
              u16* __restrict__ SWP, u16* __restrict__ CW, float* __restrict__ SBS) {
  __shared__ float As[32][256];
  const int bx = blockIdx.x;
  const int tid = threadIdx.x;

  if (bx < 304) {
    // ---- compose W'_i = (R_{i-1} + I) @ W_i,tap -> fragment-packed ----
    int chunk = bx & 7, tap = (bx >> 3) & 1, bi = bx >> 4;  // bi 0..18
    int i = bi + 1;
    int co = tid;
    int ci0 = chunk * 32;

    for (int idx = tid; idx < 32 * 256; idx += 256) {
      int r = idx >> 8, m = idx & 255;
      float v = res_w[((size_t)(bi * 256 + ci0 + r)) * 256 + m];
      if (ci0 + r == m) v += 1.0f;
      As[r][m] = v;
    }
    __syncthreads();

    float acc[32];
    #pragma unroll
    for (int r = 0; r < 32; ++r) acc[r] = 0.0f;

    const float* Wb = dil_w + ((size_t)(i * 2 + tap) * 256) * 256 + co;
    for (int m4 = 0; m4 < 64; ++m4) {
      const float* wp = Wb + (size_t)m4 * 4 * 256;
      float w0 = wp[0], w1 = wp[256], w2 = wp[512], w3 = wp[768];
      #pragma unroll
      for (int r = 0; r < 32; ++r) {
        float4 a = *(const float4*)&As[r][m4 * 4];
        acc[r] = fmaf(a.x, w0, acc[r]);
        acc[r] = fmaf(a.y, w1, acc[r]);
        acc[r] = fmaf(a.z, w2, acc[r]);
        acc[r] = fmaf(a.w, w3, acc[r]);
      }
    }
    int kb = tap * 8 + chunk;
    int kt = kb >> 1, ks = kb & 1;
    int ny = co >> 7, wn = (co >> 6) & 1, fn = (co >> 4) & 3, fr = co & 15;
    u16* ob = DWP + (size_t)bi * 131072 + kt * 16384 + ks * 8192 +
              ny * 4096 + wn * 2048 + fn * 512 + fr * 8;
    #pragma unroll
    for (int g = 0; g < 4; ++g) {
      u16 tmp[8];
      #pragma unroll
      for (int jj = 0; jj < 8; ++jj) tmp[jj] = f2b(acc[g * 8 + jj]);
      *(uint4*)(ob + g * 128) = *(uint4*)tmp;
    }
  } else if (bx < 304 + 5120) {
    // ---- pack_skipT: fragment-packed SWP ----
    int e = (bx - 304) * 256 + tid;
    int co = e & 255, ci = (e >> 8) & 255, i = e >> 16;
    int kk = ci >> 6, ks = (ci >> 5) & 1, fq = (ci >> 3) & 3, jj = ci & 7;
    int ny = co >> 7, wn = (co >> 6) & 1, fn = (co >> 4) & 3, fr = co & 15;
    int lane = fq * 16 + fr;
    SWP[(size_t)i * 65536 + kk * 16384 + ks * 8192 + ny * 4096 + wn * 2048 +
        fn * 512 + lane * 8 + jj] = f2b(skip_w[e]);
  } else if (bx < 304 + 5120 + 256) {
    // ---- pack_cls ----
    int e = (bx - 5424) * 256 + tid;
    int co = e & 255, ci = e >> 8;
    CW[(size_t)co * 256 + ci] = f2b(cls_w[e]);
  } else if (bx < 5680 + 19) {
    // ---- compose_bias ----
    int bi = bx - 5680, i = bi + 1, co = tid;
    float acc = dil_b[(size_t)i * 256 + co];
    const float* W0 = dil_w + ((size_t)(i * 2 + 0) * 256) * 256;
    const float* W1 = dil_w + ((size_t)(i * 2 + 1) * 256) * 256;
    for (int m = 0; m < 256; ++m) {
      float rb = res_b[(size_t)bi * 256 + m];
      acc = fmaf(rb, W0[(size_t)m * 256 + co] + W1[(size_t)m * 256 + co], acc);
    }
    Bc[(size_t)bi * 256 + co] = acc;
  } else if (bx == 5699) {
    // ---- head0: block-0 rank-1 fold ----
    int co = tid;
    float u0 = 0.f, u1 = 0.f, b0 = dil_b[co];
    for (int m = 0; m < 256; ++m) {
      float cwm = causal_w[m], cbm = causal_b[m];
      float w0 = dil_w[(size_t)m * 256 + co];
      float w1 = dil_w[(size_t)(256 + m) * 256 + co];
      u0 = fmaf(cwm, w0, u0);
      u1 = fmaf(cwm, w1, u1);
      b0 = fmaf(cbm, w0 + w1, b0);
    }
    U[co] = u0; U[256 + co] = u1; U[512 + co] = b0;
  } else {
    // ---- sbsum ----
    int n = tid;
    float s = 0.f;
    for (int i = 0; i < 20; ++i) s += skip_b[(size_t)i * 256 + n];
    SBS[n] = s;
  }
}

// ---- G0[b][t][c] = gate(in[t]*u0 + in[t+1]*u1 + b0) ----
__global__ __launch_bounds__(256)
void g0_init(const float* __restrict__ in, const float* __restrict__ U,
             u16* __restrict__ G0) {
  int t = blockIdx.x, b = blockIdx.y, co = threadIdx.x;
  float x0 = in[(size_t)b * LFULL + t];
  float x1 = in[(size_t)b * LFULL + t + 1];
  float h = fmaf(x0, U[co], fmaf(x1, U[256 + co], U[512 + co]));
  G0[((size_t)b * LFULL + t) * CCH + co] = f2b(gatef(h));
}

// ===== HOT: gate GEMM, BM=64. A: LDS 3-buf 2-deep; B: packed L2->reg =======
// 4 waves as 2x2; wave tile 32x64 (fm 0-1, fn 0-3).
__global__ __launch_bounds__(256)
void gatem(const u16* __restrict__ Ain, int d, int Tout, int ntile,
           const u16* __restrict__ Wp, const float* __restrict__ bias,
           u16* __restrict__ Gout) {
  __shared__ u16 As[3][BM * 64];            // 24 KB

  const int tid = threadIdx.x;
  const int nwg = ntile * 16;
  const int wgid = xcd_swz(blockIdx.x, nwg);
  const int tx = wgid % ntile;
  const int rem = wgid / ntile;
  const int ny = rem & 1;
  const int bb = rem >> 1;

  const int t0 = tx * BM;
  const int n0 = ny * BN;
  const int lane = tid & 63, wv = tid >> 6;
  const int wm = wv >> 1, wn = wv & 1;
  const int fr = lane & 15, fq = lane >> 4;
  const int rl = lane >> 3;
  const int subx = ((lane & 7) ^ rl) * 8;
  const int rowb = wv * 16;                 // each wave stages 16 rows

  const u16* Ab = Ain + (size_t)bb * XSTR;
  const u16* Wbase = Wp + (size_t)ny * 4096 + wn * 2048 + lane * 8;

  f32x4 acc[2][4];
  #pragma unroll
  for (int fn = 0; fn < 4; ++fn) {
    float4 bv = *(const float4*)&bias[n0 + wn * 64 + fn * 16 + fq * 4];
    #pragma unroll
    for (int fm = 0; fm < 2; ++fm) acc[fm][fn] = (f32x4){bv.x, bv.y, bv.z, bv.w};
  }

  auto STAGE_A = [&](int kt, int sel) {
    const int tap = kt >> 2, ks0 = (kt & 3) * 64;
    #pragma unroll
    for (int qq = 0; qq < 2; ++qq) {
      int rr = rowb + qq * 8 + rl;
      int t = t0 + rr;
      if (t > Tout - 1) t = Tout - 1;
      glds16(Ab + (size_t)(t + tap * d) * CCH + ks0 + subx,
             &As[sel][(rowb + qq * 8) * 64]);
    }
  };
  auto LOADB = [&](int kt, short8* br) {
    const u16* base = Wbase + (size_t)kt * 16384;
    #pragma unroll
    for (int ks = 0; ks < 2; ++ks)
      #pragma unroll
      for (int fn = 0; fn < 4; ++fn)
        br[fn * 2 + ks] = *(const short8*)(base + ks * 8192 + fn * 512);
  };

  short8 b0r[8], b1r[8];
  LOADB(0, b0r);        // queue: B0(8)
  STAGE_A(0, 0);        // +A0(2)
  STAGE_A(1, 1);        // +A1(2) = 12

  // steady queue entering wait: A(kt)2,B(kt)8,A(kt+1)2,B(kt+1)8,A(kt+2)2 = 22
  // vmcnt(12) drains exactly A(kt)+B(kt).
  #pragma unroll
  for (int kt = 0; kt < 8; ++kt) {
    short8* bc = (kt & 1) ? b1r : b0r;
    short8* bn = (kt & 1) ? b0r : b1r;
    if (kt < 7) LOADB(kt + 1, bn);
    if (kt < 6) {
      STAGE_A(kt + 2, (kt + 2) % 3);
      asm volatile("s_waitcnt vmcnt(12)" ::: "memory");
    } else if (kt == 6) {
      asm volatile("s_waitcnt vmcnt(10)" ::: "memory");
    } else {
      asm volatile("s_waitcnt vmcnt(0)" ::: "memory");
    }
    __builtin_amdgcn_s_barrier();
    __builtin_amdgcn_sched_barrier(0);

    const int cur = kt % 3;
    #pragma unroll
    for (int ks = 0; ks < 2; ++ks) {
      short8 af[2];
      #pragma unroll
      for (int fm = 0; fm < 2; ++fm) {
        int row = wm * 32 + fm * 16 + fr;
        af[fm] = *(const short8*)&As[cur][row * 64 + ((ks * 4 + fq) ^ (row & 7)) * 8];
      }
      #pragma unroll
      for (int fm = 0; fm < 2; ++fm)
        #pragma unroll
        for (int fn = 0; fn < 4; ++fn)
          acc[fm][fn] = __builtin_amdgcn_mfma_f32_16x16x32_bf16(   // SWAPPED ->
              bc[fn * 2 + ks], af[fm], acc[fm][fn], 0, 0, 0);      // D^T layout
    }
    __builtin_amdgcn_s_barrier();
  }

  // D^T: t = t0+wm*32+fm*16+fr ; cout quad = n0+wn*64+fn*16+fq*4
  u16* Ob = Gout + (size_t)bb * XSTR;
  #pragma unroll
  for (int fm = 0; fm < 2; ++fm) {
    int t = t0 + wm * 32 + fm * 16 + fr;
    if (t >= Tout) continue;
    #pragma unroll
    for (int fn = 0; fn < 4; ++fn) {
      int c0 = n0 + wn * 64 + fn * 16 + fq * 4;
      f32x4 a = acc[fm][fn];
      uint32 p0 = (uint32)f2b(gatef(a[0])) | ((uint32)f2b(gatef(a[1])) << 16);
      uint32 p1 = (uint32)f2b(gatef(a[2])) | ((uint32)f2b(gatef(a[3])) << 16);
      uint2 pk; pk.x = p0; pk.y = p1;
      *(uint2*)(Ob + (size_t)t * CCH + c0) = pk;
    }
  }
}

// ===== HOT: deferred-skip mega-GEMM, BM=64, 3-buf 2-deep A + packed B ======
__global__ __launch_bounds__(256)
void skipm(const u16* __restrict__ Gh, const u16* __restrict__ SWP,
           float* __restrict__ P) {
  __shared__ u16 As[3][BM * 64];

  const int tid = threadIdx.x;
  const int stile = 33;                     // ceil(2050/64)
  const int nwg = stile * 2 * 32;
  const int wgid = xcd_swz(blockIdx.x, nwg);
  const int tx = wgid % stile;
  const int rem = wgid / stile;
  const int ny = rem & 1;
  const int zz = rem >> 1;
  const int b = zz >> 2, j = zz & 3;

  const int t0 = tx * BM;
  const int n0 = ny * BN;
  const int lane = tid & 63, wv = tid >> 6;
  const int wm = wv >> 1, wn = wv & 1;
  const int fr = lane & 15, fq = lane >> 4;
  const int rl = lane >> 3;
  const int subx = ((lane & 7) ^ rl) * 8;
  const int rowb = wv * 16;

  const u16* Gb = Gh + (size_t)b * XSTR;
  const u16* Wbase = SWP + (size_t)ny * 4096 + wn * 2048 + lane * 8;

  f32x4 acc[2][4];
  #pragma unroll
  for (int fm = 0; fm < 2; ++fm)
    #pragma unroll
    for (int fn = 0; fn < 4; ++fn) acc[fm][fn] = (f32x4){0.f, 0.f, 0.f, 0.f};

  auto STAGE_A = [&](int kt, int sel) {
    const int i = j * 5 + (kt >> 2);
    const int toff = TOUT[i] - SKL;
    const int ks0 = (kt & 3) * 64;
    const u16* Gi = Gb + (size_t)i * GSTRIDE;
    #pragma unroll
    for (int qq = 0; qq < 2; ++qq) {
      int rr = rowb + qq * 8 + rl;
      int t = t0 + rr;
      if (t > SKL - 1) t = SKL - 1;
      glds16(Gi + (size_t)(toff + t) * CCH + ks0 + subx,
             &As[sel][(rowb + qq * 8) * 64]);
    }
  };
  auto LOADB = [&](int kt, short8* br) {
    const int i = j * 5 + (kt >> 2), kk = kt & 3;
    const u16* base = Wbase + (size_t)i * 65536 + kk * 16384;
    #pragma unroll
    for (int ks = 0; ks < 2; ++ks)
      #pragma unroll
      for (int fn = 0; fn < 4; ++fn)
        br[fn * 2 + ks] = *(const short8*)(base + ks * 8192 + fn * 512);
  };

  short8 b0r[8], b1r[8];
  LOADB(0, b0r);
  STAGE_A(0, 0);
  STAGE_A(1, 1);

  #pragma unroll
  for (int kt = 0; kt < 20; ++kt) {
    short8* bc = (kt & 1) ? b1r : b0r;
    short8* bn = (kt & 1) ? b0r : b1r;
    if (kt < 19) LOADB(kt + 1, bn);
    if (kt < 18) {
      STAGE_A(kt + 2, (kt + 2) % 3);
      asm volatile("s_waitcnt vmcnt(12)" ::: "memory");
    } else if (kt == 18) {
      asm volatile("s_waitcnt vmcnt(10)" ::: "memory");
    } else {
      asm volatile("s_waitcnt vmcnt(0)" ::: "memory");
    }
    __builtin_amdgcn_s_barrier();
    __builtin_amdgcn_sched_barrier(0);

    const int cur = kt % 3;
    #pragma unroll
    for (int ks = 0; ks < 2; ++ks) {
      short8 af[2];
      #pragma unroll
      for (int fm = 0; fm < 2; ++fm) {
        int row = wm * 32 + fm * 16 + fr;
        af[fm] = *(const short8*)&As[cur][row * 64 + ((ks * 4 + fq) ^ (row & 7)) * 8];
      }
      #pragma unroll
      for (int fm = 0; fm < 2; ++fm)
        #pragma unroll
        for (int fn = 0; fn < 4; ++fn)
          acc[fm][fn] = __builtin_amdgcn_mfma_f32_16x16x32_bf16(
              bc[fn * 2 + ks], af[fm], acc[fm][fn], 0, 0, 0);   // D^T
    }
    __builtin_amdgcn_s_barrier();
  }

  float* Pj = P + (size_t)j * PSTR + (size_t)b * SSTR;
  #pragma unroll
  for (int fm = 0; fm < 2; ++fm) {
    int t = t0 + wm * 32 + fm * 16 + fr;
    if (t >= SKL) continue;
    #pragma unroll
    for (int fn = 0; fn < 4; ++fn) {
      int c0 = n0 + wn * 64 + fn * 16 + fq * 4;
      f32x4 a = acc[fm][fn];
      float4 o = {a[0], a[1], a[2], a[3]};
      *(float4*)(Pj + (size_t)t * CCH + c0) = o;
    }
  }
}

// ============ cold cls GEMMs: reg-staged (transform fused in stage) ========
enum { MODE_CLS1 = 1, MODE_CLS2 = 2 };

template <int MODE>
__global__ __launch_bounds__(256)
void convm(const void* __restrict__ Ainv, long a_bstride,
           const u16* __restrict__ Wt, const float* __restrict__ bias,
           const float* __restrict__ extra,
           void* __restrict__ Out1, long out_bstride, int Tout) {
  __shared__ u16 As[128 * LDKC];
  __shared__ u16 Bs[128 * LDKC];

  const int tid = threadIdx.x;
  const int bb  = blockIdx.z;
  const int t0  = blockIdx.x * 128;
  const int n0  = blockIdx.y * 128;
  const int lane = tid & 63, wv = tid >> 6;
  const int wm = wv >> 1, wn = wv & 1;
  const int fr = lane & 15, fq = lane >> 4;

  f32x4 acc[4][4];
  #pragma unroll
  for (int fn = 0; fn < 4; ++fn) {
    float bv = bias[n0 + wn * 64 + fn * 16 + fr];
    #pragma unroll
    for (int fm = 0; fm < 4; ++fm) acc[fm][fn] = (f32x4){bv, bv, bv, bv};
  }

  for (int kt = 0; kt < 4; ++kt) {
    for (int idx = tid; idx < 1024; idx += 256) {
      int r = idx >> 3, c8 = idx & 7;
      int t = t0 + r; if (t > Tout - 1) t = Tout - 1;
      uint4 v;
      if constexpr (MODE == MODE_CLS1) {
        const float* p0 = (const float*)Ainv + (size_t)bb * a_bstride +
                          (size_t)t * CCH + kt * 64 + c8 * 8;
        float4 s0 = *(const float4*)p0;
        float4 s1 = *(const float4*)(p0 + 4);
        #pragma unroll
        for (int jj = 1; jj < 4; ++jj) {
          const float* pj = p0 + (size_t)jj * PSTR;
          float4 a0 = *(const float4*)pj;
          float4 a1 = *(const float4*)(pj + 4);
          s0.x += a0.x; s0.y += a0.y; s0.z += a0.z; s0.w += a0.w;
          s1.x += a1.x; s1.y += a1.y; s1.z += a1.z; s1.w += a1.w;
        }
        float4 e0 = *(const float4*)&extra[kt * 64 + c8 * 8];
        float4 e1 = *(const float4*)&extra[kt * 64 + c8 * 8 + 4];
        u16 tmp[8];
        tmp[0] = f2b(fmaxf((s0.x + e0.x) * 0.05f, 0.f));
        tmp[1] = f2b(fmaxf((s0.y + e0.y) * 0.05f, 0.f));
        tmp[2] = f2b(fmaxf((s0.z + e0.z) * 0.05f, 0.f));
        tmp[3] = f2b(fmaxf((s0.w + e0.w) * 0.05f, 0.f));
        tmp[4] = f2b(fmaxf((s1.x + e1.x) * 0.05f, 0.f));
        tmp[5] = f2b(fmaxf((s1.y + e1.y) * 0.05f, 0.f));
        tmp[6] = f2b(fmaxf((s1.z + e1.z) * 0.05f, 0.f));
        tmp[7] = f2b(fmaxf((s1.w + e1.w) * 0.05f, 0.f));
        v = *(uint4*)tmp;
      } else {
        const u16* sp = (const u16*)Ainv + (size_t)bb * a_bstride +
                        (size_t)t * CCH + kt * 64 + c8 * 8;
        uint4 raw = *(const uint4*)sp;
        u16 tmp[8];
        *(uint4*)tmp = raw;
        #pragma unroll
        for (int jj = 0; jj < 8; ++jj) tmp[jj] = (tmp[jj] & 0x8000) ? (u16)0 : tmp[jj];
        v = *(uint4*)tmp;
      }
      *(uint4*)&As[r * LDKC + c8 * 8] = v;
    }
    for (int idx = tid; idx < 1024; idx += 256) {
      int r = idx >> 3, c8 = idx & 7;
      const u16* sp = Wt + (size_t)(n0 + r) * 256 + kt * 64 + c8 * 8;
      *(uint4*)&Bs[r * LDKC + c8 * 8] = *(const uint4*)sp;
    }
    __syncthreads();

    #pragma unroll
    for (int ks = 0; ks < 2; ++ks) {
      short8 af[4], bfr[4];
      #pragma unroll
      for (int fm = 0; fm < 4; ++fm)
        af[fm] = *(const short8*)&As[(wm * 64 + fm * 16 + fr) * LDKC + ks * 32 + fq * 8];
      #pragma unroll
      for (int fn = 0; fn < 4; ++fn)
        bfr[fn] = *(const short8*)&Bs[(wn * 64 + fn * 16 + fr) * LDKC + ks * 32 + fq * 8];
      #pragma unroll
      for (int fm = 0; fm < 4; ++fm)
        #pragma unroll
        for (int fn = 0; fn < 4; ++fn)
          acc[fm][fn] = __builtin_amdgcn_mfma_f32_16x16x32_bf16(
              af[fm], bfr[fn], acc[fm][fn], 0, 0, 0);
    }
    __syncthreads();
  }

  #pragma unroll
  for (int fm = 0; fm < 4; ++fm) {
    int rbase = t0 + wm * 64 + fm * 16 + fq * 4;
    #pragma unroll
    for (int r = 0; r < 4; ++r) {
      int t = rbase + r;
      if (t >= Tout) continue;
      #pragma unroll
      for (int fn = 0; fn < 4; ++fn) {
        int c = n0 + wn * 64 + fn * 16 + fr;
        float a = acc[fm][fn][r];
        size_t oix = (size_t)bb * out_bstride + (size_t)t * CCH + c;
        if constexpr (MODE == MODE_CLS1) {
          ((u16*)Out1)[oix] = f2b(a);
        } else {
          ((float*)Out1)[oix] = a;
        }
      }
    }
  }
}

// ---------------- dense head (fp32, memory-bound on 537MB weights) --------
__global__ __launch_bounds__(256)
void dense_partial(const float* __restrict__ f, const float* __restrict__ W,
                   float* __restrict__ part) {
  int tstep = blockIdx.x;
  int n = threadIdx.x;
  __shared__ float fs[BATCH][CCH];
  for (int idx = threadIdx.x; idx < BATCH * CCH; idx += 256) {
    int b = idx >> 8, c = idx & 255;
    fs[b][c] = f[((size_t)b * SKL + tstep) * CCH + c];
  }
  __syncthreads();
  float acc[BATCH] = {0.f, 0.f, 0.f, 0.f, 0.f, 0.f, 0.f, 0.f};
  const float* Wr = W + (size_t)tstep * CCH * CCH;
  for (int ci = 0; ci < CCH; ++ci) {
    float w = Wr[(size_t)ci * CCH + n];
    #pragma unroll
    for (int b = 0; b < BATCH; ++b) acc[b] = fmaf(fs[b][ci], w, acc[b]);
  }
  #pragma unroll
  for (int b = 0; b < BATCH; ++b)
    part[((size_t)tstep * BATCH + b) * CCH + n] = acc[b];
}

__global__ __launch_bounds__(256)
void reduce_part(const float* __restrict__ part, float* __restrict__ part2) {
  int chunk = blockIdx.x, b = blockIdx.y, n = threadIdx.x;
  int c0 = chunk * 33;
  int c1 = c0 + 33; if (c1 > SKL) c1 = SKL;
  float s = 0.f;
  for (int c = c0; c < c1; ++c) s += part[((size_t)c * BATCH + b) * CCH + n];
  part2[((size_t)b * 64 + chunk) * CCH + n] = s;
}

__global__ __launch_bounds__(256)
void softmax_k(const float* __restrict__ part2, const float* __restrict__ db,
               float* __restrict__ out) {
  int b = blockIdx.x, n = threadIdx.x;
  float s = db[n];
  for (int ch = 0; ch < 64; ++ch) s += part2[((size_t)b * 64 + ch) * CCH + n];

  __shared__ float r4[4];
  __shared__ float mglob, sglob;
  int wid = n >> 6, lane = n & 63;

  float m = s;
  #pragma unroll
  for (int off = 1; off < 64; off <<= 1) m = fmaxf(m, __shfl_xor(m, off));
  if (lane == 0) r4[wid] = m;
  __syncthreads();
  if (n == 0) mglob = fmaxf(fmaxf(r4[0], r4[1]), fmaxf(r4[2], r4[3]));
  __syncthreads();

  float e = expf(s - mglob);
  float se = e;
  #pragma unroll
  for (int off = 1; off < 64; off <<= 1) se += __shfl_xor(se, off);
  if (lane == 0) r4[wid] = se;
  __syncthreads();
  if (n == 0) sglob = r4[0] + r4[1] + r4[2] + r4[3];
  __syncthreads();

  out[(size_t)b * CCH + n] = e / sglob;
}

extern "C" void kernel_launch(void* const* d_in, const int* in_sizes, int n_in,
                              void* d_out, int out_size, void* d_ws, size_t ws_size,
                              hipStream_t stream) {
  const float* input_x  = (const float*)d_in[0];
  const float* causal_w = (const float*)d_in[1];
  const float* causal_b = (const float*)d_in[2];
  const float* dil_w    = (const float*)d_in[3];
  const float* dil_b    = (const float*)d_in[4];
  const float* res_w    = (const float*)d_in[5];
  const float* res_b    = (const float*)d_in[6];
  const float* skip_w   = (const float*)d_in[7];
  const float* skip_b   = (const float*)d_in[8];
  const float* cls_w    = (const float*)d_in[9];
  const float* cls_b    = (const float*)d_in[10];
  const float* dense_w  = (const float*)d_in[11];
  const float* dense_b  = (const float*)d_in[12];
  float* out = (float*)d_out;

  // ---- workspace layout ----
  char* p = (char*)d_ws;
  u16*   Gh    = (u16*)p;   p += GSTRIDE * 20 * 2;                 // 335 MB
  float* P     = (float*)p; p += PSTR * 4 * 4;                     // 67 MB
  u16*   S1    = (u16*)p;   p += (size_t)BATCH * SKL * CCH * 2;
  float* S2    = (float*)p; p += (size_t)BATCH * SKL * CCH * 4;
  float* PART  = (float*)p; p += (size_t)SKL * BATCH * CCH * 4;
  float* PART2 = (float*)p; p += (size_t)BATCH * 64 * CCH * 4;
  u16*   DWP   = (u16*)p;   p += (size_t)19 * 131072 * 2;
  float* Bc    = (float*)p; p += (size_t)19 * 256 * 4;
  u16*   SWP   = (u16*)p;   p += (size_t)20 * 65536 * 2;
  u16*   CW    = (u16*)p;   p += (size_t)256 * 256 * 2;
  float* U     = (float*)p; p += (size_t)768 * 4;
  float* SBS   = (float*)p; p += (size_t)256 * 4;

  static const int dil[20] = {1, 2, 4, 8, 16, 32, 64, 128, 256, 512,
                              1, 2, 4, 8, 16, 32, 64, 128, 256, 512};
  static const int tout_h[20] = {4095,4093,4089,4081,4065,4033,3969,3841,3585,3073,
                                 3072,3070,3066,3058,3042,3010,2946,2818,2562,2050};
  dim3 blk(256);

  // merged prep: compose_w(304) | pack_skipT(5120) | pack_cls(256) |
  //              compose_bias(19) | head0(1) | sbsum(1)
  prep_all<<<dim3(5701), blk, 0, stream>>>(
      res_w, dil_w, dil_b, res_b, causal_w, causal_b, skip_w, cls_w, skip_b,
      DWP, Bc, U, SWP, CW, SBS);

  g0_init<<<dim3(4095, BATCH), blk, 0, stream>>>(input_x, U, Gh);

  // 19 composed gate GEMMs (BM=64, 1D swizzled grid)
  for (int i = 1; i < 20; ++i) {
    int Tout = tout_h[i];
    int ntile = (Tout + BM - 1) / BM;
    gatem<<<dim3(ntile * 16), blk, 0, stream>>>(
        Gh + (size_t)(i - 1) * GSTRIDE, dil[i], Tout, ntile,
        DWP + (size_t)(i - 1) * 131072, Bc + (size_t)(i - 1) * 256,
        Gh + (size_t)i * GSTRIDE);
  }

  // deferred skip mega-GEMM (K=5120 split x4 into fp32 partials, write-once)
  skipm<<<dim3(33 * 2 * 32), blk, 0, stream>>>(Gh, SWP, P);

  const int ctile = (SKL + 127) / 128;   // 17 cls tiles (BM=128 kernel)
  convm<MODE_CLS1><<<dim3(ctile, 2, BATCH), blk, 0, stream>>>(
      P, (long)SSTR, CW, cls_b, SBS, S1, (long)SSTR, SKL);
  convm<MODE_CLS2><<<dim3(ctile, 2, BATCH), blk, 0, stream>>>(
      S1, (long)SSTR, CW, cls_b, nullptr, S2, (long)SSTR, SKL);

  dense_partial<<<dim3(SKL), blk, 0, stream>>>(S2, dense_w, PART);
  reduce_part<<<dim3(64, BATCH), blk, 0, stream>>>(PART, PART2);
  softmax_k<<<dim3(BATCH), blk, 0, stream>>>(PART2, dense_b, out);
}